// Round 5
// baseline (572.265 us; speedup 1.0000x reference)
//
#include <hip/hip_runtime.h>
#include <math.h>

#define Bn 64
#define In 2048
#define On 2048
#define Sn 10
#define Cn 512

#define KT 64                // K per stage
#define NSTG (In / KT)       // 32
#define LROW 72              // KT + 8 pad (bf16 elems)

typedef short short8 __attribute__((ext_vector_type(8)));
typedef float f32x4 __attribute__((ext_vector_type(4)));

__device__ __forceinline__ unsigned short f2bf(float f) {
    union { float f; unsigned u; } v; v.f = f;
    unsigned r = (v.u + 0x7FFFu + ((v.u >> 16) & 1u)) >> 16;  // RNE
    return (unsigned short)r;
}

// blocks 0..63: ctx_signal[b] = mean(context[b,:]); blocks 64..575: x -> bf16
__global__ void prep_kernel(const float* __restrict__ x,
                            const float* __restrict__ ctx,
                            float* __restrict__ ws_ctx,
                            unsigned short* __restrict__ ws_xbf) {
    const int b = blockIdx.x;
    const int t = threadIdx.x;
    if (b < Bn) {
        __shared__ float red[256];
        red[t] = ctx[b * Cn + t] + ctx[b * Cn + t + 256];
        __syncthreads();
        for (int off = 128; off > 0; off >>= 1) {
            if (t < off) red[t] += red[t + off];
            __syncthreads();
        }
        if (t == 0) ws_ctx[b] = red[0] * (1.0f / (float)Cn);
    } else {
        int idx = (b - Bn) * 256 + t;
        ws_xbf[idx] = f2bf(x[idx]);
    }
}

// ONE WAVE per block, one o per block, full K. 3-slot register pipeline:
// ALL global loads live in load_stage; compute is pure LDS+MFMA (no vmcnt).
__global__ __launch_bounds__(64, 2)
void main_kernel(const unsigned short* __restrict__ xbf,
                 const float* __restrict__ wgt,
                 const float* __restrict__ cst,
                 const float* __restrict__ seg,
                 const float* __restrict__ prn,
                 const float* __restrict__ gates,
                 const float* __restrict__ bias,
                 const float* __restrict__ aact,
                 const float* __restrict__ athr,
                 const float* __restrict__ ws_ctx,
                 float* __restrict__ outT) {
    __shared__ __align__(16) unsigned short Blds[2][16 * LROW];  // 4608 B

    const int l = threadIdx.x;
    const int o = blockIdx.x;
    const int l15 = l & 15, q = l >> 4;
    const float pthr = prn[0];

    // zero pad rows 11..15 of both buffers (single wave: program order suffices)
    for (int idx = l; idx < 5 * LROW; idx += 64) {
        Blds[0][11 * LROW + idx] = 0;
        Blds[1][11 * LROW + idx] = 0;
    }

    // seg scatter seed: j = c*128 + 2l (even), ii = j/10, s = j%10 (even)
    const int ii0 = (2 * l) / 10;
    const int s0  = (2 * l) % 10;

    // ---- 3-slot pipeline registers ----
    float2 sv[3][5];          // seg: 640 f32/stage, lane-interleaved float2 x5
    float  wv[3], cv[3];      // synaptic weight / connection strength (1/lane)
    short8 av[3][8];          // x-frags: [mt*2 + kk2], mt<4, kk2<2

    const float* segO = seg + (size_t)o * In * Sn;
    const float* wgtO = wgt + (size_t)o * In;
    const float* cstO = cst + (size_t)o * In;

    auto load_stage = [&](int is, int sl) {
        const int k0 = is * KT;
        const float* sp = segO + (size_t)k0 * Sn + 2 * l;
#pragma unroll
        for (int c = 0; c < 5; ++c) sv[sl][c] = *(const float2*)(sp + c * 128);
        wv[sl] = wgtO[k0 + l];
        cv[sl] = cstO[k0 + l];
#pragma unroll
        for (int mt = 0; mt < 4; ++mt)
#pragma unroll
            for (int kk2 = 0; kk2 < 2; ++kk2)
                av[sl][mt * 2 + kk2] =
                    *(const short8*)(xbf + (size_t)(mt * 16 + l15) * In + k0 + kk2 * 32 + q * 8);
    };

    auto store_stage = [&](int sl, int bb) {
        int ii = ii0, s = s0;
#pragma unroll
        for (int c = 0; c < 5; ++c) {
            unsigned short* bp = &Blds[bb][s * LROW + ii];
            bp[0]    = f2bf(sv[sl][c].x);   // (row s,   col ii)
            bp[LROW] = f2bf(sv[sl][c].y);   // (row s+1, col ii)
            s += 8; ii += 12;
            if (s >= 10) { s -= 10; ++ii; }
        }
        float e = (__builtin_fabsf(wv[sl]) * cv[sl] > pthr) ? wv[sl] : 0.0f;
        Blds[bb][10 * LROW + l] = f2bf(e);
    };

    f32x4 acc[4];
#pragma unroll
    for (int n = 0; n < 4; ++n) acc[n] = (f32x4){0.f, 0.f, 0.f, 0.f};

    auto compute = [&](int sl, int bb) {
#pragma unroll
        for (int kk2 = 0; kk2 < 2; ++kk2) {
            short8 b8 = *(const short8*)&Blds[bb][l15 * LROW + kk2 * 32 + q * 8];
#pragma unroll
            for (int mt = 0; mt < 4; ++mt)
                acc[mt] = __builtin_amdgcn_mfma_f32_16x16x32_bf16(av[sl][mt * 2 + kk2], b8,
                                                                  acc[mt], 0, 0, 0);
        }
    };

    // ---- pipelined K loop: prefetch distance = 2 full iterations ----
    load_stage(0, 0);
    load_stage(1, 1);
    store_stage(0, 0);        // waits slot0 only (in-order: slot1 stays in flight)
    load_stage(2, 2);
    for (int is = 0; is < NSTG; ++is) {
        const int sl = is % 3;
        compute(sl, is & 1);                              // regs + LDS only
        if (is + 1 < NSTG) store_stage((is + 1) % 3, (is + 1) & 1);
        if (is + 3 < NSTG) load_stage(is + 3, sl);        // reuse freed slot
    }

    // ---- epilogue ----
    // lane holds acc[mt][r] at (m = mt*16 + q*4 + r, n = l15)
    float* sc = (float*)&Blds[0][0];    // [64][12] f32 scratch
    if (l15 < 12) {
#pragma unroll
        for (int mt = 0; mt < 4; ++mt)
#pragma unroll
            for (int r = 0; r < 4; ++r)
                sc[(mt * 16 + q * 4 + r) * 12 + l15] = acc[mt][r];
    }
    // single wave: LDS program order guarantees visibility
    float d[11];
#pragma unroll
    for (int j = 0; j < 11; ++j) d[j] = sc[l * 12 + j];

    float dend = 0.0f;
    const float* gp = gates + o * Sn;
#pragma unroll
    for (int s = 0; s < Sn; ++s) {
        float g = 1.0f / (1.0f + expf(-gp[s]));
        float r = d[s] > 0.0f ? d[s] : 0.0f;
        dend += r * g;
    }
    // mean_astro[o]: lane l contributes batch l, wave-reduce
    float sg = 1.0f / (1.0f + expf(-ws_ctx[l] * aact[o]));
    float contrib = (sg > athr[o]) ? sg : 0.0f;
#pragma unroll
    for (int off = 32; off > 0; off >>= 1) contrib += __shfl_xor(contrib, off);
    const float mastro = contrib * (1.0f / 64.0f);

    float val = d[10] * mastro + bias[o] + dend;
    outT[(size_t)o * Bn + l] = val > 0.0f ? val : 0.0f;   // [o][b], coalesced
}

// outT[2048][64] -> out[64][2048], coalesced both directions.
__global__ void transpose_kernel(const float* __restrict__ outT,
                                 float* __restrict__ out) {
    __shared__ float tile[64][65];
    const int t = threadIdx.x;
    const int o0 = blockIdx.x * 64;
    {
        const int b = t & 63;
        const int o4 = t >> 6;
#pragma unroll
        for (int r = 0; r < 16; ++r) {
            const int oi = o4 * 16 + r;
            tile[oi][b] = outT[(size_t)(o0 + oi) * Bn + b];
        }
    }
    __syncthreads();
    {
        const int oi = t & 63;
#pragma unroll
        for (int r = 0; r < 16; ++r) {
            const int b = (t >> 6) * 16 + r;
            out[(size_t)b * On + o0 + oi] = tile[oi][b];
        }
    }
}

extern "C" void kernel_launch(void* const* d_in, const int* in_sizes, int n_in,
                              void* d_out, int out_size, void* d_ws, size_t ws_size,
                              hipStream_t stream) {
    (void)in_sizes; (void)n_in; (void)out_size; (void)ws_size;
    const float* x    = (const float*)d_in[0];
    const float* ctx  = (const float*)d_in[1];
    // d_in[2] prev_activation: unused by the reference
    const float* wgt  = (const float*)d_in[3];
    const float* bias = (const float*)d_in[4];
    const float* aact = (const float*)d_in[5];
    const float* athr = (const float*)d_in[6];
    const float* seg  = (const float*)d_in[7];
    const float* gat  = (const float*)d_in[8];
    const float* cst  = (const float*)d_in[9];
    const float* prn  = (const float*)d_in[10];
    float* out = (float*)d_out;

    float* ws_ctx = (float*)d_ws;                                   // 64 f32
    unsigned short* ws_xbf = (unsigned short*)((char*)d_ws + 256);  // 64x2048 bf16
    float* ws_outT = (float*)((char*)d_ws + 262400);                // 2048x64 f32

    prep_kernel<<<Bn + (Bn * In) / 256, 256, 0, stream>>>(x, ctx, ws_ctx, ws_xbf);
    main_kernel<<<On, 64, 0, stream>>>(ws_xbf, wgt, cst, seg, prn, gat, bias,
                                       aact, athr, ws_ctx, ws_outT);
    transpose_kernel<<<On / 64, 256, 0, stream>>>(ws_outT, out);
}

// Round 6
// 294.818 us; speedup vs baseline: 1.9411x; 1.9411x over previous
//
#include <hip/hip_runtime.h>
#include <math.h>

#define Bn 64
#define In 2048
#define On 2048
#define Sn 10
#define Cn 512

#define KT 64                // K per stage
#define NSTG (In / KT)       // 32
#define LROW 72              // KT + 8 pad (bf16 elems)

typedef short short8 __attribute__((ext_vector_type(8)));
typedef float f32x4 __attribute__((ext_vector_type(4)));

__device__ __forceinline__ unsigned short f2bf(float f) {
    union { float f; unsigned u; } v; v.f = f;
    unsigned r = (v.u + 0x7FFFu + ((v.u >> 16) & 1u)) >> 16;  // RNE
    return (unsigned short)r;
}

// blocks 0..63: ctx_signal[b] = mean(context[b,:]); blocks 64..575: x -> bf16
__global__ void prep_kernel(const float* __restrict__ x,
                            const float* __restrict__ ctx,
                            float* __restrict__ ws_ctx,
                            unsigned short* __restrict__ ws_xbf) {
    const int b = blockIdx.x;
    const int t = threadIdx.x;
    if (b < Bn) {
        __shared__ float red[256];
        red[t] = ctx[b * Cn + t] + ctx[b * Cn + t + 256];
        __syncthreads();
        for (int off = 128; off > 0; off >>= 1) {
            if (t < off) red[t] += red[t + off];
            __syncthreads();
        }
        if (t == 0) ws_ctx[b] = red[0] * (1.0f / (float)Cn);
    } else {
        int idx = (b - Bn) * 256 + t;
        ws_xbf[idx] = f2bf(x[idx]);
    }
}

// ONE WAVE per block, one o per block, full K, no barriers.
// 2-slot register pipeline in NAMED variables (no dynamic indexing -> no spill).
__global__ __launch_bounds__(64, 2)
void main_kernel(const unsigned short* __restrict__ xbf,
                 const float* __restrict__ wgt,
                 const float* __restrict__ cst,
                 const float* __restrict__ seg,
                 const float* __restrict__ prn,
                 const float* __restrict__ gates,
                 const float* __restrict__ bias,
                 const float* __restrict__ aact,
                 const float* __restrict__ athr,
                 const float* __restrict__ ws_ctx,
                 float* __restrict__ outT) {
    __shared__ __align__(16) unsigned short Blds[2][16 * LROW];  // 4608 B

    const int l = threadIdx.x;
    const int o = blockIdx.x;
    const int l15 = l & 15, q = l >> 4;
    const float pthr = prn[0];

    // zero pad rows 11..15 of both buffers (single wave: program order suffices)
    for (int idx = l; idx < 5 * LROW; idx += 64) {
        Blds[0][11 * LROW + idx] = 0;
        Blds[1][11 * LROW + idx] = 0;
    }

    // seg scatter seed: j = c*128 + 2l (even), ii = j/10, s = j%10 (even)
    const int ii0 = (2 * l) / 10;
    const int s0  = (2 * l) % 10;

    const float* segO = seg + (size_t)o * In * Sn;
    const float* wgtO = wgt + (size_t)o * In;
    const float* cstO = cst + (size_t)o * In;

    // ---- named 2-slot pipeline state ----
    short8 av0[8], av1[8];     // x-frags [mt*2+kk2]
    float2 sv0[5], sv1[5];     // seg (lane-interleaved float2 x5)
    float  wv0, cv0, wv1, cv1;

    auto load_a = [&](int is, short8 (&av)[8]) {
        const int k0 = is * KT;
#pragma unroll
        for (int mt = 0; mt < 4; ++mt)
#pragma unroll
            for (int kk2 = 0; kk2 < 2; ++kk2)
                av[mt * 2 + kk2] =
                    *(const short8*)(xbf + (size_t)(mt * 16 + l15) * In + k0 + kk2 * 32 + q * 8);
    };
    auto load_seg = [&](int is, float2 (&sv)[5], float& wv, float& cv) {
        const int k0 = is * KT;
        const float* sp = segO + (size_t)k0 * Sn + 2 * l;
#pragma unroll
        for (int c = 0; c < 5; ++c) sv[c] = *(const float2*)(sp + c * 128);
        wv = wgtO[k0 + l];
        cv = cstO[k0 + l];
    };
    auto store_stage = [&](const float2 (&sv)[5], float wv, float cv, int bb) {
        int ii = ii0, s = s0;
#pragma unroll
        for (int c = 0; c < 5; ++c) {
            unsigned short* bp = &Blds[bb][s * LROW + ii];
            bp[0]    = f2bf(sv[c].x);   // (row s,   col ii)
            bp[LROW] = f2bf(sv[c].y);   // (row s+1, col ii)
            s += 8; ii += 12;
            if (s >= 10) { s -= 10; ++ii; }
        }
        float e = (__builtin_fabsf(wv) * cv > pthr) ? wv : 0.0f;
        Blds[bb][10 * LROW + l] = f2bf(e);
    };

    f32x4 acc[4];
#pragma unroll
    for (int n = 0; n < 4; ++n) acc[n] = (f32x4){0.f, 0.f, 0.f, 0.f};

    auto compute = [&](const short8 (&av)[8], int bb) {
#pragma unroll
        for (int kk2 = 0; kk2 < 2; ++kk2) {
            short8 b8 = *(const short8*)&Blds[bb][l15 * LROW + kk2 * 32 + q * 8];
#pragma unroll
            for (int mt = 0; mt < 4; ++mt)
                acc[mt] = __builtin_amdgcn_mfma_f32_16x16x32_bf16(av[mt * 2 + kk2], b8,
                                                                  acc[mt], 0, 0, 0);
        }
    };

    // ---- prologue ----
    load_a(0, av0); load_seg(0, sv0, wv0, cv0);
    load_a(1, av1); load_seg(1, sv1, wv1, cv1);
    store_stage(sv0, wv0, cv0, 0);          // waits seg(0) only

    // ---- steady loop (branch-free body), stages is, is+1 ----
    for (int is = 0; is < NSTG - 2; is += 2) {
        compute(av0, 0);                    // stage is     (waits a(is): 2 stages old)
        load_a(is + 2, av0);
        store_stage(sv1, wv1, cv1, 1);      // stage is+1   (waits seg(is+1): 1 stage old)
        load_seg(is + 2, sv0, wv0, cv0);
        compute(av1, 1);                    // stage is+1
        load_a(is + 3, av1);
        store_stage(sv0, wv0, cv0, 0);      // stage is+2
        load_seg(is + 3, sv1, wv1, cv1);
    }
    // ---- tail: stages 30, 31 (loads exhausted) ----
    compute(av0, 0);
    store_stage(sv1, wv1, cv1, 1);
    compute(av1, 1);

    // ---- epilogue ----
    // lane holds acc[mt][r] at (m = mt*16 + q*4 + r, n = l15)
    float* sc = (float*)&Blds[0][0];    // [64][12] f32 scratch
    if (l15 < 12) {
#pragma unroll
        for (int mt = 0; mt < 4; ++mt)
#pragma unroll
            for (int r = 0; r < 4; ++r)
                sc[(mt * 16 + q * 4 + r) * 12 + l15] = acc[mt][r];
    }
    // single wave: LDS program order guarantees visibility
    float d[11];
#pragma unroll
    for (int j = 0; j < 11; ++j) d[j] = sc[l * 12 + j];

    float dend = 0.0f;
    const float* gp = gates + o * Sn;
#pragma unroll
    for (int s = 0; s < Sn; ++s) {
        float g = 1.0f / (1.0f + expf(-gp[s]));
        float r = d[s] > 0.0f ? d[s] : 0.0f;
        dend += r * g;
    }
    // mean_astro[o]: lane l contributes batch l, wave-reduce
    float sg = 1.0f / (1.0f + expf(-ws_ctx[l] * aact[o]));
    float contrib = (sg > athr[o]) ? sg : 0.0f;
#pragma unroll
    for (int off = 32; off > 0; off >>= 1) contrib += __shfl_xor(contrib, off);
    const float mastro = contrib * (1.0f / 64.0f);

    float val = d[10] * mastro + bias[o] + dend;
    outT[(size_t)o * Bn + l] = val > 0.0f ? val : 0.0f;   // [o][b], coalesced
}

// outT[2048][64] -> out[64][2048], coalesced both directions.
__global__ void transpose_kernel(const float* __restrict__ outT,
                                 float* __restrict__ out) {
    __shared__ float tile[64][65];
    const int t = threadIdx.x;
    const int o0 = blockIdx.x * 64;
    {
        const int b = t & 63;
        const int o4 = t >> 6;
#pragma unroll
        for (int r = 0; r < 16; ++r) {
            const int oi = o4 * 16 + r;
            tile[oi][b] = outT[(size_t)(o0 + oi) * Bn + b];
        }
    }
    __syncthreads();
    {
        const int oi = t & 63;
#pragma unroll
        for (int r = 0; r < 16; ++r) {
            const int b = (t >> 6) * 16 + r;
            out[(size_t)b * On + o0 + oi] = tile[oi][b];
        }
    }
}

extern "C" void kernel_launch(void* const* d_in, const int* in_sizes, int n_in,
                              void* d_out, int out_size, void* d_ws, size_t ws_size,
                              hipStream_t stream) {
    (void)in_sizes; (void)n_in; (void)out_size; (void)ws_size;
    const float* x    = (const float*)d_in[0];
    const float* ctx  = (const float*)d_in[1];
    // d_in[2] prev_activation: unused by the reference
    const float* wgt  = (const float*)d_in[3];
    const float* bias = (const float*)d_in[4];
    const float* aact = (const float*)d_in[5];
    const float* athr = (const float*)d_in[6];
    const float* seg  = (const float*)d_in[7];
    const float* gat  = (const float*)d_in[8];
    const float* cst  = (const float*)d_in[9];
    const float* prn  = (const float*)d_in[10];
    float* out = (float*)d_out;

    float* ws_ctx = (float*)d_ws;                                   // 64 f32
    unsigned short* ws_xbf = (unsigned short*)((char*)d_ws + 256);  // 64x2048 bf16
    float* ws_outT = (float*)((char*)d_ws + 262400);                // 2048x64 f32

    prep_kernel<<<Bn + (Bn * In) / 256, 256, 0, stream>>>(x, ctx, ws_ctx, ws_xbf);
    main_kernel<<<On, 64, 0, stream>>>(ws_xbf, wgt, cst, seg, prn, gat, bias,
                                       aact, athr, ws_ctx, ws_outT);
    transpose_kernel<<<On / 64, 256, 0, stream>>>(ws_outT, out);
}